// Round 4
// baseline (812.587 us; speedup 1.0000x reference)
//
#include <hip/hip_runtime.h>
#include <cstddef>
#include <cstdint>

#define NF 512
#define SND 256
#define NG 256
#define EPSV 1e-5f

typedef __attribute__((ext_vector_type(8))) short bf16x8;
typedef __attribute__((ext_vector_type(4))) float f32x4;

__device__ __forceinline__ float bf2f(unsigned short u) {
  return __uint_as_float(((unsigned int)u) << 16);
}
__device__ __forceinline__ unsigned short f2bf(float f) {
  unsigned int u = __float_as_uint(f);
  return (unsigned short)((u + 0x7fffu + ((u >> 16) & 1u)) >> 16);
}
__device__ __forceinline__ unsigned int pack2bf(float a, float b) {
  return (unsigned int)f2bf(a) | ((unsigned int)f2bf(b) << 16);
}
__device__ __forceinline__ void unpack8(const uint4 u, float* v) {
  v[0] = __uint_as_float(u.x << 16); v[1] = __uint_as_float(u.x & 0xffff0000u);
  v[2] = __uint_as_float(u.y << 16); v[3] = __uint_as_float(u.y & 0xffff0000u);
  v[4] = __uint_as_float(u.z << 16); v[5] = __uint_as_float(u.z & 0xffff0000u);
  v[6] = __uint_as_float(u.w << 16); v[7] = __uint_as_float(u.w & 0xffff0000u);
}

__device__ __forceinline__ void async16(const unsigned short* g, unsigned short* l) {
  __builtin_amdgcn_global_load_lds(
      (const __attribute__((address_space(1))) unsigned int*)g,
      (__attribute__((address_space(3))) unsigned int*)l, 16, 0, 0);
}

// ---------------- small kernels ----------------
__global__ void offsets_kernel(const int* __restrict__ batch, int* __restrict__ offs, int M) {
  int t = threadIdx.x + blockIdx.x * blockDim.x;
  if (t > NG) return;
  if (t == NG) { offs[NG] = M; return; }
  int lo = 0, hi = M;
  while (lo < hi) { int mid = (lo + hi) >> 1; if (batch[mid] < t) lo = mid + 1; else hi = mid; }
  offs[t] = lo;
}

__global__ void wconv_kernel(const float* __restrict__ w1, const float* __restrict__ w2,
                             const float* __restrict__ w3, const float* __restrict__ w4,
                             const float* __restrict__ w5,
                             unsigned short* __restrict__ o1, unsigned short* __restrict__ o2,
                             unsigned short* __restrict__ o3, unsigned short* __restrict__ o4,
                             unsigned short* __restrict__ o5) {
  int i = threadIdx.x + blockIdx.x * 256;
  if (i < 131072) { o1[i] = f2bf(w1[i]); o5[i] = f2bf(w5[i]); }
  if (i < 65536)  { o2[i] = f2bf(w2[i]); o3[i] = f2bf(w3[i]); o4[i] = f2bf(w4[i]); }
}

// ---------------- stats: vectorized loads, LDS block-reduce, partials (NO atomics) ----------------
template <typename T, int F, int VE, bool WB, bool GLOB>
__global__ void stats_k(const T* __restrict__ X, const int* __restrict__ offs, int M,
                        float* __restrict__ ps, float* __restrict__ pq,
                        unsigned short* __restrict__ xbf) {
  constexpr int TPR = F / VE, RPB = 256 / TPR;
  const int g = GLOB ? 0 : blockIdx.x;
  const int s = GLOB ? 0 : offs[g];
  const int e = GLOB ? M : offs[g + 1];
  const int slot = threadIdx.x / TPR;
  const int f0 = (threadIdx.x % TPR) * VE;
  float a0[VE], a1[VE];
#pragma unroll
  for (int i = 0; i < VE; ++i) { a0[i] = 0.f; a1[i] = 0.f; }

  for (int r = s + (int)blockIdx.y * RPB + slot; r < e; r += (int)gridDim.y * RPB) {
    float v[VE];
    if constexpr (sizeof(T) == 2) {
      const uint4 u = *(const uint4*)((const unsigned short*)X + (size_t)r * F + f0);
      unpack8(u, v);
    } else {
      const float4 u = *(const float4*)((const float*)X + (size_t)r * F + f0);
      v[0] = u.x; v[1] = u.y; v[2] = u.z; v[3] = u.w;
    }
#pragma unroll
    for (int i = 0; i < VE; ++i) { a0[i] += v[i]; a1[i] += v[i] * v[i]; }
    if constexpr (WB) {  // bf16 copy (layer 1: fp32 -> bf16 into A buffer), VE==4
      *(uint2*)(xbf + (size_t)r * F + f0) = make_uint2(pack2bf(v[0], v[1]), pack2bf(v[2], v[3]));
    }
  }

  const int groups = GLOB ? 1 : (int)gridDim.x;
  const size_t pbase = (size_t)blockIdx.y * ((size_t)groups * F) + (size_t)g * F + f0;

  __shared__ float red[256 * VE];  // [slot][F]
  __syncthreads();
#pragma unroll
  for (int i = 0; i < VE; ++i) red[slot * F + f0 + i] = a0[i];
  __syncthreads();
  if (slot == 0) {
    float t[VE];
#pragma unroll
    for (int i = 0; i < VE; ++i) {
      t[i] = 0.f;
      for (int sl = 0; sl < RPB; ++sl) t[i] += red[sl * F + f0 + i];
    }
#pragma unroll
    for (int i = 0; i < VE; i += 4)
      *(float4*)&ps[pbase + i] = make_float4(t[i], t[i + 1], t[i + 2], t[i + 3]);
  }
  __syncthreads();
#pragma unroll
  for (int i = 0; i < VE; ++i) red[slot * F + f0 + i] = a1[i];
  __syncthreads();
  if (slot == 0) {
    float t[VE];
#pragma unroll
    for (int i = 0; i < VE; ++i) {
      t[i] = 0.f;
      for (int sl = 0; sl < RPB; ++sl) t[i] += red[sl * F + f0 + i];
    }
#pragma unroll
    for (int i = 0; i < VE; i += 4)
      *(float4*)&pq[pbase + i] = make_float4(t[i], t[i + 1], t[i + 2], t[i + 3]);
  }
}

// Per-graph finalize: P small (4/8), grid covers groups*F threads.
__global__ void finalize_kernel(const float* __restrict__ ps, const float* __restrict__ pq,
                                const float* __restrict__ w, const float* __restrict__ b,
                                const float* __restrict__ ms, const int* __restrict__ offs,
                                int F, int P,
                                float* __restrict__ sc, float* __restrict__ sh) {
  int idx = threadIdx.x + blockIdx.x * 256;
  int g = idx / F, f = idx - g * F;
  int total = (int)gridDim.x * 256;
  float s0 = 0.f, s1 = 0.f;
  for (int p = 0; p < P; ++p) {
    s0 += ps[(size_t)p * total + idx];
    s1 += pq[(size_t)p * total + idx];
  }
  float cnt = fmaxf((float)(offs[g + 1] - offs[g]), 1.0f);
  float mean = s0 / cnt;
  float ex2  = s1 / cnt;
  float mm = mean * ms[f];
  float var = ex2 - 2.f * mm * mean + mm * mm;  // E[(x-mean*ms)^2]
  float rstd = rsqrtf(var + EPSV);
  float s = w[f] * rstd;
  sc[idx] = s;
  sh[idx] = b[f] - mm * s;
}

// GLOB finalize: P large (512). 16 blocks x (16 p-lanes x 16 features), LDS combine.
__global__ void finalize_glob_kernel(const float* __restrict__ ps, const float* __restrict__ pq,
                                     const float* __restrict__ w, const float* __restrict__ b,
                                     const float* __restrict__ ms, int cnt_i, int F, int P,
                                     float* __restrict__ sc, float* __restrict__ sh) {
  const int fl = threadIdx.x & 15;
  const int pl = threadIdx.x >> 4;  // 0..15
  const int f = blockIdx.x * 16 + fl;
  float s0 = 0.f, s1 = 0.f;
  for (int p = pl; p < P; p += 16) {
    s0 += ps[(size_t)p * F + f];
    s1 += pq[(size_t)p * F + f];
  }
  __shared__ float r0[16][16], r1[16][16];
  r0[pl][fl] = s0;
  r1[pl][fl] = s1;
  __syncthreads();
  if (pl == 0) {
#pragma unroll
    for (int k = 1; k < 16; ++k) { s0 += r0[k][fl]; s1 += r1[k][fl]; }
    float cnt = fmaxf((float)cnt_i, 1.0f);
    float mean = s0 / cnt;
    float ex2  = s1 / cnt;
    float mm = mean * ms[f];
    float var = ex2 - 2.f * mm * mean + mm * mm;
    float rstd = rsqrtf(var + EPSV);
    float s = w[f] * rstd;
    sc[f] = s;
    sh[f] = b[f] - mm * s;
  }
}

// ---------------- fused GraphNorm(+PReLU) + bf16 MFMA GEMM ----------------
// A is the RAW (un-normalized) bf16 activation; normalization v = v*sc[g][k]+sh[g][k]
// (+ optional prelu) is applied in registers while staging the A tile into LDS.
// B side stays on global_load_lds. LDS image (incl. XOR swizzle) identical to before.
// out[m][n] = sum_k norm(A[m][k])*B[n][k] + lb[n]  (opt: +resid, *0.5; fp32 or bf16 out)
template <int K, bool PRELU, bool GLOB, bool RESID, bool OUT_BF>
__global__ __launch_bounds__(256, 3)
void gemm_gn_bf16(const unsigned short* __restrict__ A, const int* __restrict__ batch,
                  const float* __restrict__ SC, const float* __restrict__ SH,
                  const float* __restrict__ pa,
                  const unsigned short* __restrict__ Bw,
                  const float* __restrict__ lb_, const unsigned short* __restrict__ resid,
                  void* __restrict__ outv, int M, int N) {
  __shared__ __align__(16) unsigned short sA[128 * 64];
  __shared__ __align__(16) unsigned short sB[128 * 64];
  const int tid = threadIdx.x;
  const int wave = tid >> 6, lane = tid & 63;
  const int m0 = blockIdx.y * 128, n0 = blockIdx.x * 128;
  const int wm = wave & 1, wn = wave >> 1;
  const int qd = lane >> 4, l15 = lane & 15;

  const int srow = lane >> 3;        // 0..7
  const int schunk = lane & 7;       // physical LDS chunk this lane fills
  const int gchunk = schunk ^ srow;  // logical/global source chunk (swizzle)

  const float alpha = PRELU ? pa[0] : 0.f;

  // per-i row info (hoisted out of the K loop)
  int gidx[4];
  const unsigned short* arow[4];
#pragma unroll
  for (int i = 0; i < 4; ++i) {
    const int grow = m0 + wave * 32 + i * 8 + srow;
    const int rc = grow < M ? grow : M - 1;  // pad rows: clamp batch index
    gidx[i] = GLOB ? 0 : batch[rc];
    arow[i] = A + (size_t)grow * K;
  }

  f32x4 acc[4][4];
#pragma unroll
  for (int mi = 0; mi < 4; ++mi)
#pragma unroll
    for (int ni = 0; ni < 4; ++ni) acc[mi][ni] = (f32x4){0.f, 0.f, 0.f, 0.f};

  const unsigned short* Bbase = Bw + (size_t)n0 * K;

  for (int kt = 0; kt < K / 64; ++kt) {
    const int kOff = kt * 64 + gchunk * 8;
    // B: async DMA into LDS (overlaps A-side register work below)
#pragma unroll
    for (int i = 0; i < 4; ++i) {
      const int r = wave * 32 + i * 8 + srow;
      async16(Bbase + (size_t)r * K + kOff, &sB[(wave * 4 + i) * 512]);
    }
    // A: reg-stage + fused normalize (+prelu), ds_write to the same swizzled image
#pragma unroll
    for (int i = 0; i < 4; ++i) {
      const uint4 u = *(const uint4*)(arow[i] + kOff);
      const float* scp = SC + (size_t)gidx[i] * K + kOff;
      const float* shp = SH + (size_t)gidx[i] * K + kOff;
      const float4 c0 = *(const float4*)scp;
      const float4 c1 = *(const float4*)(scp + 4);
      const float4 h0 = *(const float4*)shp;
      const float4 h1 = *(const float4*)(shp + 4);
      float v[8];
      unpack8(u, v);
      v[0] = fmaf(v[0], c0.x, h0.x); v[1] = fmaf(v[1], c0.y, h0.y);
      v[2] = fmaf(v[2], c0.z, h0.z); v[3] = fmaf(v[3], c0.w, h0.w);
      v[4] = fmaf(v[4], c1.x, h1.x); v[5] = fmaf(v[5], c1.y, h1.y);
      v[6] = fmaf(v[6], c1.z, h1.z); v[7] = fmaf(v[7], c1.w, h1.w);
      if (PRELU) {
#pragma unroll
        for (int j = 0; j < 8; ++j) v[j] = v[j] >= 0.f ? v[j] : alpha * v[j];
      }
      *(uint4*)&sA[(wave * 4 + i) * 512 + lane * 8] =
          make_uint4(pack2bf(v[0], v[1]), pack2bf(v[2], v[3]),
                     pack2bf(v[4], v[5]), pack2bf(v[6], v[7]));
    }
    __syncthreads();  // drains vmcnt (B DMA) + lgkmcnt (A ds_write)
#pragma unroll
    for (int ks = 0; ks < 2; ++ks) {
      bf16x8 af[4], bfr[4];
      const int pc = ((ks * 4 + qd) ^ (l15 & 7)) * 8;
#pragma unroll
      for (int mi = 0; mi < 4; ++mi)
        af[mi] = *(const bf16x8*)&sA[(wm * 64 + mi * 16 + l15) * 64 + pc];
#pragma unroll
      for (int ni = 0; ni < 4; ++ni)
        bfr[ni] = *(const bf16x8*)&sB[(wn * 64 + ni * 16 + l15) * 64 + pc];
#pragma unroll
      for (int mi = 0; mi < 4; ++mi)
#pragma unroll
        for (int ni = 0; ni < 4; ++ni)
          acc[mi][ni] = __builtin_amdgcn_mfma_f32_16x16x32_bf16(af[mi], bfr[ni], acc[mi][ni], 0, 0, 0);
    }
    __syncthreads();
  }

  // epilogue: C/D row = qd*4+i (m), col = l15 (n)
  float lb[4];
#pragma unroll
  for (int ni = 0; ni < 4; ++ni) lb[ni] = lb_[n0 + wn * 64 + ni * 16 + l15];
  float* outF = (float*)outv;
  unsigned short* outH = (unsigned short*)outv;
#pragma unroll
  for (int mi = 0; mi < 4; ++mi) {
#pragma unroll
    for (int i = 0; i < 4; ++i) {
      const int row = m0 + wm * 64 + mi * 16 + qd * 4 + i;
      if (row >= M) continue;
#pragma unroll
      for (int ni = 0; ni < 4; ++ni) {
        const int col = n0 + wn * 64 + ni * 16 + l15;
        float v = acc[mi][ni][i] + lb[ni];
        if (RESID) v = 0.5f * (v + bf2f(resid[(size_t)row * N + col]));
        if (OUT_BF) outH[(size_t)row * N + col] = f2bf(v);
        else        outF[(size_t)row * N + col] = v;
      }
    }
  }
}

// ---------------- launch ----------------
extern "C" void kernel_launch(void* const* d_in, const int* in_sizes, int n_in,
                              void* d_out, int out_size, void* d_ws, size_t ws_size,
                              hipStream_t stream) {
  const float* x    = (const float*)d_in[0];
  const int* batch  = (const int*)d_in[1];
  const float* gw1 = (const float*)d_in[2],  *gb1 = (const float*)d_in[3],  *gm1 = (const float*)d_in[4];
  const float* gw2 = (const float*)d_in[5],  *gb2 = (const float*)d_in[6],  *gm2 = (const float*)d_in[7];
  const float* gw3 = (const float*)d_in[8],  *gb3 = (const float*)d_in[9],  *gm3 = (const float*)d_in[10];
  const float* gw4 = (const float*)d_in[11], *gb4 = (const float*)d_in[12], *gm4 = (const float*)d_in[13];
  const float* gw5 = (const float*)d_in[14], *gb5 = (const float*)d_in[15], *gm5 = (const float*)d_in[16];
  const float* W1 = (const float*)d_in[17], *b1 = (const float*)d_in[18];
  const float* W2 = (const float*)d_in[19], *b2 = (const float*)d_in[20];
  const float* W3 = (const float*)d_in[21], *b3 = (const float*)d_in[22];
  const float* W4 = (const float*)d_in[23], *b4 = (const float*)d_in[24];
  const float* W5 = (const float*)d_in[25], *b5 = (const float*)d_in[26];
  const float* a2 = (const float*)d_in[27], *a3 = (const float*)d_in[28];
  const float* a4 = (const float*)d_in[29], *a5 = (const float*)d_in[30];
  float* out = (float*)d_out;
  (void)n_in; (void)out_size; (void)ws_size;

  const int M = in_sizes[0] / NF;
  const int MT = (M + 127) / 128;
  const int M_pad = MT * 128;

  char* wsp = (char*)d_ws;
  size_t off = 0;
  auto take = [&](size_t bytes) -> void* {
    void* p = wsp + off;
    off = (off + bytes + 255) & ~(size_t)255;
    return p;
  };
  int* offs            = (int*)take((NG + 1) * sizeof(int));
  unsigned short* Wb1  = (unsigned short*)take((size_t)SND * NF * 2);
  unsigned short* Wb2  = (unsigned short*)take((size_t)SND * SND * 2);
  unsigned short* Wb3  = (unsigned short*)take((size_t)SND * SND * 2);
  unsigned short* Wb4  = (unsigned short*)take((size_t)SND * SND * 2);
  unsigned short* Wb5  = (unsigned short*)take((size_t)NF * SND * 2);
  // partial buffers (no atomics): max = layer-1, gy=8 -> 8*NG*NF floats = 4 MB each
  float* psum          = (float*)take((size_t)8 * NG * NF * 4);
  float* psq           = (float*)take((size_t)8 * NG * NF * 4);
  float* sc            = (float*)take((size_t)NG * NF * 4);
  float* sh            = (float*)take((size_t)NG * NF * 4);
  unsigned short* B1   = (unsigned short*)take((size_t)M_pad * SND * 2);
  unsigned short* B2   = (unsigned short*)take((size_t)M_pad * SND * 2);
  unsigned short* Abuf = (unsigned short*)take((size_t)M_pad * NF * 2);
  unsigned short* A3   = Abuf;  // reused as M_pad x SND after layer 1/2 consume Abuf

  offsets_kernel<<<2, 256, 0, stream>>>(batch, offs, M);
  wconv_kernel<<<512, 256, 0, stream>>>(W1, W2, W3, W4, W5, Wb1, Wb2, Wb3, Wb4, Wb5);

  // ---- layer 1: x1 = lin1(gn1(x, batch))  [stats emits raw bf16(x) into Abuf] ----
  stats_k<float, NF, 4, true, false><<<dim3(NG, 8), 256, 0, stream>>>(x, offs, M, psum, psq, Abuf);
  finalize_kernel<<<(NG * NF) / 256, 256, 0, stream>>>(psum, psq, gw1, gb1, gm1, offs, NF, 8, sc, sh);
  gemm_gn_bf16<NF, false, false, false, true><<<dim3(SND / 128, MT), 256, 0, stream>>>(
      Abuf, batch, sc, sh, nullptr, Wb1, b1, nullptr, B1, M, SND);

  // ---- layer 2: h = lin2(prelu(gn2(x1, batch), a2)) ----
  stats_k<unsigned short, SND, 8, false, false><<<dim3(NG, 4), 256, 0, stream>>>(B1, offs, M, psum, psq, nullptr);
  finalize_kernel<<<(NG * SND) / 256, 256, 0, stream>>>(psum, psq, gw2, gb2, gm2, offs, SND, 4, sc, sh);
  gemm_gn_bf16<SND, true, false, false, true><<<dim3(SND / 128, MT), 256, 0, stream>>>(
      B1, batch, sc, sh, a2, Wb2, b2, nullptr, B2, M, SND);

  // ---- layer 3: x2 = (lin3(prelu(gn3_global(h), a3)) + x1) / 2 -> A3 (=Abuf) ----
  stats_k<unsigned short, SND, 8, false, true><<<dim3(1, 512), 256, 0, stream>>>(B2, offs, M, psum, psq, nullptr);
  finalize_glob_kernel<<<SND / 16, 256, 0, stream>>>(psum, psq, gw3, gb3, gm3, M, SND, 512, sc, sh);
  gemm_gn_bf16<SND, true, true, true, true><<<dim3(SND / 128, MT), 256, 0, stream>>>(
      B2, nullptr, sc, sh, a3, Wb3, b3, B1, A3, M, SND);

  // ---- layer 4: x3 = (lin4(prelu(gn4(x2, batch), a4)) + x2) / 2 -> B1 ----
  stats_k<unsigned short, SND, 8, false, false><<<dim3(NG, 4), 256, 0, stream>>>(A3, offs, M, psum, psq, nullptr);
  finalize_kernel<<<(NG * SND) / 256, 256, 0, stream>>>(psum, psq, gw4, gb4, gm4, offs, SND, 4, sc, sh);
  gemm_gn_bf16<SND, true, false, true, true><<<dim3(SND / 128, MT), 256, 0, stream>>>(
      A3, batch, sc, sh, a4, Wb4, b4, A3, B1, M, SND);

  // ---- layer 5: out = lin5(prelu(gn5(x3, batch), a5)), fp32 out, N=512 ----
  stats_k<unsigned short, SND, 8, false, false><<<dim3(NG, 4), 256, 0, stream>>>(B1, offs, M, psum, psq, nullptr);
  finalize_kernel<<<(NG * SND) / 256, 256, 0, stream>>>(psum, psq, gw5, gb5, gm5, offs, SND, 4, sc, sh);
  gemm_gn_bf16<SND, true, false, false, false><<<dim3(NF / 128, MT), 256, 0, stream>>>(
      B1, batch, sc, sh, a5, Wb5, b5, nullptr, out, M, NF);
}

// Round 5
// 775.499 us; speedup vs baseline: 1.0478x; 1.0478x over previous
//
#include <hip/hip_runtime.h>
#include <cstddef>
#include <cstdint>

#define NF 512
#define SND 256
#define NG 256
#define EPSV 1e-5f

typedef __attribute__((ext_vector_type(8))) short bf16x8;
typedef __attribute__((ext_vector_type(4))) float f32x4;

__device__ __forceinline__ float bf2f(unsigned short u) {
  return __uint_as_float(((unsigned int)u) << 16);
}
__device__ __forceinline__ unsigned short f2bf(float f) {
  unsigned int u = __float_as_uint(f);
  return (unsigned short)((u + 0x7fffu + ((u >> 16) & 1u)) >> 16);
}
__device__ __forceinline__ unsigned int pack2bf(float a, float b) {
  return (unsigned int)f2bf(a) | ((unsigned int)f2bf(b) << 16);
}
__device__ __forceinline__ void unpack8(const uint4 u, float* v) {
  v[0] = __uint_as_float(u.x << 16); v[1] = __uint_as_float(u.x & 0xffff0000u);
  v[2] = __uint_as_float(u.y << 16); v[3] = __uint_as_float(u.y & 0xffff0000u);
  v[4] = __uint_as_float(u.z << 16); v[5] = __uint_as_float(u.z & 0xffff0000u);
  v[6] = __uint_as_float(u.w << 16); v[7] = __uint_as_float(u.w & 0xffff0000u);
}

__device__ __forceinline__ void async16(const unsigned short* g, unsigned short* l) {
  __builtin_amdgcn_global_load_lds(
      (const __attribute__((address_space(1))) unsigned int*)g,
      (__attribute__((address_space(3))) unsigned int*)l, 16, 0, 0);
}

// ---------------- small kernels ----------------
__global__ void offsets_kernel(const int* __restrict__ batch, int* __restrict__ offs, int M) {
  int t = threadIdx.x + blockIdx.x * blockDim.x;
  if (t > NG) return;
  if (t == NG) { offs[NG] = M; return; }
  int lo = 0, hi = M;
  while (lo < hi) { int mid = (lo + hi) >> 1; if (batch[mid] < t) lo = mid + 1; else hi = mid; }
  offs[t] = lo;
}

__global__ void wconv_kernel(const float* __restrict__ w1, const float* __restrict__ w2,
                             const float* __restrict__ w3, const float* __restrict__ w4,
                             const float* __restrict__ w5,
                             unsigned short* __restrict__ o1, unsigned short* __restrict__ o2,
                             unsigned short* __restrict__ o3, unsigned short* __restrict__ o4,
                             unsigned short* __restrict__ o5) {
  int i = threadIdx.x + blockIdx.x * 256;
  if (i < 131072) { o1[i] = f2bf(w1[i]); o5[i] = f2bf(w5[i]); }
  if (i < 65536)  { o2[i] = f2bf(w2[i]); o3[i] = f2bf(w3[i]); o4[i] = f2bf(w4[i]); }
}

// ---------------- stats: vectorized loads, LDS block-reduce, partials (NO atomics) ----------------
template <typename T, int F, int VE, bool WB, bool GLOB>
__global__ void stats_k(const T* __restrict__ X, const int* __restrict__ offs, int M,
                        float* __restrict__ ps, float* __restrict__ pq,
                        unsigned short* __restrict__ xbf) {
  constexpr int TPR = F / VE, RPB = 256 / TPR;
  const int g = GLOB ? 0 : blockIdx.x;
  const int s = GLOB ? 0 : offs[g];
  const int e = GLOB ? M : offs[g + 1];
  const int slot = threadIdx.x / TPR;
  const int f0 = (threadIdx.x % TPR) * VE;
  float a0[VE], a1[VE];
#pragma unroll
  for (int i = 0; i < VE; ++i) { a0[i] = 0.f; a1[i] = 0.f; }

  for (int r = s + (int)blockIdx.y * RPB + slot; r < e; r += (int)gridDim.y * RPB) {
    float v[VE];
    if constexpr (sizeof(T) == 2) {
      const uint4 u = *(const uint4*)((const unsigned short*)X + (size_t)r * F + f0);
      unpack8(u, v);
    } else {
      const float4 u = *(const float4*)((const float*)X + (size_t)r * F + f0);
      v[0] = u.x; v[1] = u.y; v[2] = u.z; v[3] = u.w;
    }
#pragma unroll
    for (int i = 0; i < VE; ++i) { a0[i] += v[i]; a1[i] += v[i] * v[i]; }
    if constexpr (WB) {  // bf16 copy (layer 1: fp32 -> bf16 into A buffer), VE==4
      *(uint2*)(xbf + (size_t)r * F + f0) = make_uint2(pack2bf(v[0], v[1]), pack2bf(v[2], v[3]));
    }
  }

  const int groups = GLOB ? 1 : (int)gridDim.x;
  const size_t pbase = (size_t)blockIdx.y * ((size_t)groups * F) + (size_t)g * F + f0;

  __shared__ float red[256 * VE];  // [slot][F]
  __syncthreads();
#pragma unroll
  for (int i = 0; i < VE; ++i) red[slot * F + f0 + i] = a0[i];
  __syncthreads();
  if (slot == 0) {
    float t[VE];
#pragma unroll
    for (int i = 0; i < VE; ++i) {
      t[i] = 0.f;
      for (int sl = 0; sl < RPB; ++sl) t[i] += red[sl * F + f0 + i];
    }
#pragma unroll
    for (int i = 0; i < VE; i += 4)
      *(float4*)&ps[pbase + i] = make_float4(t[i], t[i + 1], t[i + 2], t[i + 3]);
  }
  __syncthreads();
#pragma unroll
  for (int i = 0; i < VE; ++i) red[slot * F + f0 + i] = a1[i];
  __syncthreads();
  if (slot == 0) {
    float t[VE];
#pragma unroll
    for (int i = 0; i < VE; ++i) {
      t[i] = 0.f;
      for (int sl = 0; sl < RPB; ++sl) t[i] += red[sl * F + f0 + i];
    }
#pragma unroll
    for (int i = 0; i < VE; i += 4)
      *(float4*)&pq[pbase + i] = make_float4(t[i], t[i + 1], t[i + 2], t[i + 3]);
  }
}

// Per-graph finalize: P small (4/8), grid covers groups*F threads.
__global__ void finalize_kernel(const float* __restrict__ ps, const float* __restrict__ pq,
                                const float* __restrict__ w, const float* __restrict__ b,
                                const float* __restrict__ ms, const int* __restrict__ offs,
                                int F, int P,
                                float* __restrict__ sc, float* __restrict__ sh) {
  int idx = threadIdx.x + blockIdx.x * 256;
  int g = idx / F, f = idx - g * F;
  int total = (int)gridDim.x * 256;
  float s0 = 0.f, s1 = 0.f;
  for (int p = 0; p < P; ++p) {
    s0 += ps[(size_t)p * total + idx];
    s1 += pq[(size_t)p * total + idx];
  }
  float cnt = fmaxf((float)(offs[g + 1] - offs[g]), 1.0f);
  float mean = s0 / cnt;
  float ex2  = s1 / cnt;
  float mm = mean * ms[f];
  float var = ex2 - 2.f * mm * mean + mm * mm;  // E[(x-mean*ms)^2]
  float rstd = rsqrtf(var + EPSV);
  float s = w[f] * rstd;
  sc[idx] = s;
  sh[idx] = b[f] - mm * s;
}

// GLOB finalize: P large (512). 16 blocks x (16 p-lanes x 16 features), LDS combine.
__global__ void finalize_glob_kernel(const float* __restrict__ ps, const float* __restrict__ pq,
                                     const float* __restrict__ w, const float* __restrict__ b,
                                     const float* __restrict__ ms, int cnt_i, int F, int P,
                                     float* __restrict__ sc, float* __restrict__ sh) {
  const int fl = threadIdx.x & 15;
  const int pl = threadIdx.x >> 4;  // 0..15
  const int f = blockIdx.x * 16 + fl;
  float s0 = 0.f, s1 = 0.f;
  for (int p = pl; p < P; p += 16) {
    s0 += ps[(size_t)p * F + f];
    s1 += pq[(size_t)p * F + f];
  }
  __shared__ float r0[16][16], r1[16][16];
  r0[pl][fl] = s0;
  r1[pl][fl] = s1;
  __syncthreads();
  if (pl == 0) {
#pragma unroll
    for (int k = 1; k < 16; ++k) { s0 += r0[k][fl]; s1 += r1[k][fl]; }
    float cnt = fmaxf((float)cnt_i, 1.0f);
    float mean = s0 / cnt;
    float ex2  = s1 / cnt;
    float mm = mean * ms[f];
    float var = ex2 - 2.f * mm * mean + mm * mm;
    float rstd = rsqrtf(var + EPSV);
    float s = w[f] * rstd;
    sc[f] = s;
    sh[f] = b[f] - mm * s;
  }
}

// ---------------- normalize (+prelu): bf16 in -> bf16 out, streaming ----------------
template <int K, bool PRELU, bool GLOB>
__global__ void norm_act(const unsigned short* __restrict__ Xin, unsigned short* __restrict__ Aout,
                         const float* __restrict__ SC, const float* __restrict__ SH,
                         const int* __restrict__ batch, const float* __restrict__ pa, int M) {
  constexpr int TPR = K / 8, RPB = 256 / TPR;
  const int row = blockIdx.x * RPB + threadIdx.x / TPR;
  if (row >= M) return;
  const int f0 = (threadIdx.x % TPR) * 8;
  const int g = GLOB ? 0 : batch[row];
  const float a = PRELU ? pa[0] : 0.f;
  const uint4 u = *(const uint4*)(Xin + (size_t)row * K + f0);
  const float4 s0 = *(const float4*)(SC + (size_t)g * K + f0);
  const float4 s1 = *(const float4*)(SC + (size_t)g * K + f0 + 4);
  const float4 h0 = *(const float4*)(SH + (size_t)g * K + f0);
  const float4 h1 = *(const float4*)(SH + (size_t)g * K + f0 + 4);
  float v[8];
  unpack8(u, v);
  v[0] = fmaf(v[0], s0.x, h0.x); v[1] = fmaf(v[1], s0.y, h0.y);
  v[2] = fmaf(v[2], s0.z, h0.z); v[3] = fmaf(v[3], s0.w, h0.w);
  v[4] = fmaf(v[4], s1.x, h1.x); v[5] = fmaf(v[5], s1.y, h1.y);
  v[6] = fmaf(v[6], s1.z, h1.z); v[7] = fmaf(v[7], s1.w, h1.w);
  if (PRELU) {
#pragma unroll
    for (int i = 0; i < 8; ++i) v[i] = v[i] >= 0.f ? v[i] : a * v[i];
  }
  *(uint4*)(Aout + (size_t)row * K + f0) =
      make_uint4(pack2bf(v[0], v[1]), pack2bf(v[2], v[3]),
                 pack2bf(v[4], v[5]), pack2bf(v[6], v[7]));
}

// ---------------- clean bf16 MFMA GEMM, global_load_lds + XOR swizzle ----------------
// XCD-chunked bijective blockIdx swizzle (T1/m204): column-siblings sharing an A
// row-panel and consecutive row-panels land on the SAME XCD -> A re-read and the
// B weight panel are served from that XCD's L2 instead of HBM/L3.
template <int K, bool RESID, bool OUT_BF>
__global__ __launch_bounds__(256, 4)
void gemm_bf16(const unsigned short* __restrict__ A, const unsigned short* __restrict__ Bw,
               const float* __restrict__ lb_, const unsigned short* __restrict__ resid,
               void* __restrict__ outv, int M, int N) {
  __shared__ __align__(16) unsigned short sA[128 * 64];
  __shared__ __align__(16) unsigned short sB[128 * 64];
  const int tid = threadIdx.x;
  const int wave = tid >> 6, lane = tid & 63;

  // bijective XCD swizzle: physical bid (round-robins over 8 XCDs) -> logical
  // block id such that each XCD owns a contiguous logical chunk.
  const int gx = (int)gridDim.x;
  const int nwg = gx * (int)gridDim.y;
  const int bid = (int)blockIdx.y * gx + (int)blockIdx.x;
  const int q = nwg >> 3, r = nwg & 7;
  const int xcd = bid & 7, ii = bid >> 3;
  const int logical = (xcd < r) ? xcd * (q + 1) + ii : r * (q + 1) + (xcd - r) * q + ii;
  const int bx = logical % gx;
  const int by = logical / gx;

  const int m0 = by * 128, n0 = bx * 128;
  const int wm = wave & 1, wn = wave >> 1;
  const int qd = lane >> 4, l15 = lane & 15;

  const int srow = lane >> 3;        // 0..7
  const int schunk = lane & 7;       // physical LDS chunk this lane fills
  const int gchunk = schunk ^ srow;  // logical/global source chunk (swizzle)

  f32x4 acc[4][4];
#pragma unroll
  for (int mi = 0; mi < 4; ++mi)
#pragma unroll
    for (int ni = 0; ni < 4; ++ni) acc[mi][ni] = (f32x4){0.f, 0.f, 0.f, 0.f};

  const unsigned short* Abase = A + (size_t)m0 * K;
  const unsigned short* Bbase = Bw + (size_t)n0 * K;

  for (int kt = 0; kt < K / 64; ++kt) {
    const int kOff = kt * 64 + gchunk * 8;
#pragma unroll
    for (int i = 0; i < 4; ++i) {
      const int r2 = wave * 32 + i * 8 + srow;
      async16(Abase + (size_t)r2 * K + kOff, &sA[(wave * 4 + i) * 512]);
      async16(Bbase + (size_t)r2 * K + kOff, &sB[(wave * 4 + i) * 512]);
    }
    __syncthreads();
#pragma unroll
    for (int ks = 0; ks < 2; ++ks) {
      bf16x8 af[4], bfr[4];
      const int pc = ((ks * 4 + qd) ^ (l15 & 7)) * 8;
#pragma unroll
      for (int mi = 0; mi < 4; ++mi)
        af[mi] = *(const bf16x8*)&sA[(wm * 64 + mi * 16 + l15) * 64 + pc];
#pragma unroll
      for (int ni = 0; ni < 4; ++ni)
        bfr[ni] = *(const bf16x8*)&sB[(wn * 64 + ni * 16 + l15) * 64 + pc];
#pragma unroll
      for (int mi = 0; mi < 4; ++mi)
#pragma unroll
        for (int ni = 0; ni < 4; ++ni)
          acc[mi][ni] = __builtin_amdgcn_mfma_f32_16x16x32_bf16(af[mi], bfr[ni], acc[mi][ni], 0, 0, 0);
    }
    __syncthreads();
  }

  float lb[4];
#pragma unroll
  for (int ni = 0; ni < 4; ++ni) lb[ni] = lb_[n0 + wn * 64 + ni * 16 + l15];
  float* outF = (float*)outv;
  unsigned short* outH = (unsigned short*)outv;
#pragma unroll
  for (int mi = 0; mi < 4; ++mi) {
#pragma unroll
    for (int i = 0; i < 4; ++i) {
      const int row = m0 + wm * 64 + mi * 16 + qd * 4 + i;
      if (row >= M) continue;
#pragma unroll
      for (int ni = 0; ni < 4; ++ni) {
        const int col = n0 + wn * 64 + ni * 16 + l15;
        float v = acc[mi][ni][i] + lb[ni];
        if (RESID) v = 0.5f * (v + bf2f(resid[(size_t)row * N + col]));
        if (OUT_BF) outH[(size_t)row * N + col] = f2bf(v);
        else        outF[(size_t)row * N + col] = v;
      }
    }
  }
}

// ---------------- launch ----------------
extern "C" void kernel_launch(void* const* d_in, const int* in_sizes, int n_in,
                              void* d_out, int out_size, void* d_ws, size_t ws_size,
                              hipStream_t stream) {
  const float* x    = (const float*)d_in[0];
  const int* batch  = (const int*)d_in[1];
  const float* gw1 = (const float*)d_in[2],  *gb1 = (const float*)d_in[3],  *gm1 = (const float*)d_in[4];
  const float* gw2 = (const float*)d_in[5],  *gb2 = (const float*)d_in[6],  *gm2 = (const float*)d_in[7];
  const float* gw3 = (const float*)d_in[8],  *gb3 = (const float*)d_in[9],  *gm3 = (const float*)d_in[10];
  const float* gw4 = (const float*)d_in[11], *gb4 = (const float*)d_in[12], *gm4 = (const float*)d_in[13];
  const float* gw5 = (const float*)d_in[14], *gb5 = (const float*)d_in[15], *gm5 = (const float*)d_in[16];
  const float* W1 = (const float*)d_in[17], *b1 = (const float*)d_in[18];
  const float* W2 = (const float*)d_in[19], *b2 = (const float*)d_in[20];
  const float* W3 = (const float*)d_in[21], *b3 = (const float*)d_in[22];
  const float* W4 = (const float*)d_in[23], *b4 = (const float*)d_in[24];
  const float* W5 = (const float*)d_in[25], *b5 = (const float*)d_in[26];
  const float* a2 = (const float*)d_in[27], *a3 = (const float*)d_in[28];
  const float* a4 = (const float*)d_in[29], *a5 = (const float*)d_in[30];
  float* out = (float*)d_out;
  (void)n_in; (void)out_size; (void)ws_size;

  const int M = in_sizes[0] / NF;
  const int MT = (M + 127) / 128;
  const int M_pad = MT * 128;

  char* wsp = (char*)d_ws;
  size_t off = 0;
  auto take = [&](size_t bytes) -> void* {
    void* p = wsp + off;
    off = (off + bytes + 255) & ~(size_t)255;
    return p;
  };
  int* offs            = (int*)take((NG + 1) * sizeof(int));
  unsigned short* Wb1  = (unsigned short*)take((size_t)SND * NF * 2);
  unsigned short* Wb2  = (unsigned short*)take((size_t)SND * SND * 2);
  unsigned short* Wb3  = (unsigned short*)take((size_t)SND * SND * 2);
  unsigned short* Wb4  = (unsigned short*)take((size_t)SND * SND * 2);
  unsigned short* Wb5  = (unsigned short*)take((size_t)NF * SND * 2);
  // partial buffers (no atomics): max = layer-1, gy=8 -> 8*NG*NF floats = 4 MB each
  float* psum          = (float*)take((size_t)8 * NG * NF * 4);
  float* psq           = (float*)take((size_t)8 * NG * NF * 4);
  float* sc            = (float*)take((size_t)NG * NF * 4);
  float* sh            = (float*)take((size_t)NG * NF * 4);
  unsigned short* B1   = (unsigned short*)take((size_t)M_pad * SND * 2);
  unsigned short* B2   = (unsigned short*)take((size_t)M_pad * SND * 2);
  unsigned short* Abuf = (unsigned short*)take((size_t)M_pad * NF * 2);

  offsets_kernel<<<2, 256, 0, stream>>>(batch, offs, M);
  wconv_kernel<<<512, 256, 0, stream>>>(W1, W2, W3, W4, W5, Wb1, Wb2, Wb3, Wb4, Wb5);

  // ---- layer 1: x1 = lin1(gn1(x, batch))  [stats also emits bf16(x) into Abuf] ----
  stats_k<float, NF, 4, true, false><<<dim3(NG, 8), 256, 0, stream>>>(x, offs, M, psum, psq, Abuf);
  finalize_kernel<<<(NG * NF) / 256, 256, 0, stream>>>(psum, psq, gw1, gb1, gm1, offs, NF, 8, sc, sh);
  norm_act<NF, false, false><<<(M + 3) / 4, 256, 0, stream>>>(Abuf, Abuf, sc, sh, batch, nullptr, M);
  gemm_bf16<NF, false, true><<<dim3(SND / 128, MT), 256, 0, stream>>>(Abuf, Wb1, b1, nullptr, B1, M, SND);

  // ---- layer 2: h = lin2(prelu(gn2(x1, batch), a2)) ----
  stats_k<unsigned short, SND, 8, false, false><<<dim3(NG, 4), 256, 0, stream>>>(B1, offs, M, psum, psq, nullptr);
  finalize_kernel<<<(NG * SND) / 256, 256, 0, stream>>>(psum, psq, gw2, gb2, gm2, offs, SND, 4, sc, sh);
  norm_act<SND, true, false><<<(M + 7) / 8, 256, 0, stream>>>(B1, Abuf, sc, sh, batch, a2, M);
  gemm_bf16<SND, false, true><<<dim3(SND / 128, MT), 256, 0, stream>>>(Abuf, Wb2, b2, nullptr, B2, M, SND);

  // ---- layer 3: x2 = (lin3(prelu(gn3_global(h), a3)) + x1) / 2 ----
  stats_k<unsigned short, SND, 8, false, true><<<dim3(1, 512), 256, 0, stream>>>(B2, offs, M, psum, psq, nullptr);
  finalize_glob_kernel<<<SND / 16, 256, 0, stream>>>(psum, psq, gw3, gb3, gm3, M, SND, 512, sc, sh);
  norm_act<SND, true, true><<<(M + 7) / 8, 256, 0, stream>>>(B2, Abuf, sc, sh, nullptr, a3, M);
  gemm_bf16<SND, true, true><<<dim3(SND / 128, MT), 256, 0, stream>>>(Abuf, Wb3, b3, B1, B2, M, SND);

  // ---- layer 4: x3 = (lin4(prelu(gn4(x2, batch), a4)) + x2) / 2 ----
  stats_k<unsigned short, SND, 8, false, false><<<dim3(NG, 4), 256, 0, stream>>>(B2, offs, M, psum, psq, nullptr);
  finalize_kernel<<<(NG * SND) / 256, 256, 0, stream>>>(psum, psq, gw4, gb4, gm4, offs, SND, 4, sc, sh);
  norm_act<SND, true, false><<<(M + 7) / 8, 256, 0, stream>>>(B2, Abuf, sc, sh, batch, a4, M);
  gemm_bf16<SND, true, true><<<dim3(SND / 128, MT), 256, 0, stream>>>(Abuf, Wb4, b4, B2, B1, M, SND);

  // ---- layer 5: out = lin5(prelu(gn5(x3, batch), a5)), fp32 out ----
  stats_k<unsigned short, SND, 8, false, false><<<dim3(NG, 4), 256, 0, stream>>>(B1, offs, M, psum, psq, nullptr);
  finalize_kernel<<<(NG * SND) / 256, 256, 0, stream>>>(psum, psq, gw5, gb5, gm5, offs, SND, 4, sc, sh);
  norm_act<SND, true, false><<<(M + 7) / 8, 256, 0, stream>>>(B1, Abuf, sc, sh, batch, a5, M);
  gemm_bf16<SND, false, false><<<dim3(NF / 128, MT), 256, 0, stream>>>(Abuf, Wb5, b5, nullptr, out, M, NF);
}